// Round 1
// baseline (7656.523 us; speedup 1.0000x reference)
//
#include <hip/hip_runtime.h>
#include <hip/hip_bf16.h>

// ConvGRU temporal encoder: B=8, T=16, H=W=128, hc=32, k=3 SAME.
// Layer0: cin = 1(x) + 32(h).  Layer1: cin = 32(h0) + 32(h1).
// gates conv: Cout=64 (r=ch[0:32], z=ch[32:64]); cand conv: Cout=32.
// h_new = (1-z)*h + z*tanh(conv([x, r*h]) + cb)

#define HH 128
#define WW 128
#define HW 16384
#define BB 8
#define TT 16

// ---------------- weight transpose: [cout][cin][tap] -> [cin*9+tap][cout] ---
__global__ void transpose_w(const float* __restrict__ w, float* __restrict__ out,
                            int cout, int cin)
{
    int i = blockIdx.x * 256 + threadIdx.x;
    int total = cout * cin * 9;
    if (i >= total) return;
    int tap = i % 9;
    int t2  = i / 9;
    int ci  = t2 % cin;
    int co  = t2 / cin;
    out[(ci * 9 + tap) * cout + co] = w[i];
}

// ---------------- per-channel 3x3 accumulate ------------------------------
// p: input channel plane (HxW). off/msk: precomputed clamped tap offsets and
// 0/1 masks. wrow: 9*COUT transposed weights (uniform address -> s_load).
template<int COUT>
__device__ __forceinline__ void accum(const float* __restrict__ p,
                                      const int* __restrict__ off,
                                      const float* __restrict__ msk,
                                      const float* __restrict__ wrow,
                                      float* __restrict__ acc)
{
    float v[9];
#pragma unroll
    for (int t = 0; t < 9; ++t) v[t] = p[off[t]] * msk[t];
#pragma unroll
    for (int t = 0; t < 9; ++t) {
        const float iv = v[t];
#pragma unroll
        for (int co = 0; co < COUT; ++co)
            acc[co] = fmaf(iv, wrow[t * COUT + co], acc[co]);
    }
}

__device__ __forceinline__ void make_taps(int px, int py, int* off, float* msk)
{
#pragma unroll
    for (int ky = 0; ky < 3; ++ky) {
#pragma unroll
        for (int kx = 0; kx < 3; ++kx) {
            int yy = py + ky - 1;
            int xx = px + kx - 1;
            bool ok = (yy >= 0) && (yy < HH) && (xx >= 0) && (xx < WW);
            off[ky * 3 + kx] = ok ? (yy * WW + xx) : 0;
            msk[ky * 3 + kx] = ok ? 1.0f : 0.0f;
        }
    }
}

__device__ __forceinline__ float sigmoid_f(float a)
{
    return 1.0f / (1.0f + __expf(-a));   // exp overflow -> inf -> 0, safe
}

__device__ __forceinline__ float tanh_f(float a)
{
    float e2 = __expf(2.0f * a);         // inf-safe: 1 - 2/(inf+1) = 1
    return 1.0f - 2.0f / (e2 + 1.0f);
}

// ---------------- gates kernel: z, r*h ------------------------------------
template<int CINX>
__global__ __launch_bounds__(256, 2)
void gates_kernel(const float* __restrict__ x, long xbs,
                  const float* __restrict__ h,      // [B,32,H,W]
                  const float* __restrict__ wt,     // [(CINX+32)*9][64]
                  const float* __restrict__ bias,   // [64]
                  float* __restrict__ zout,         // [B,32,H,W]
                  float* __restrict__ rhout)        // [B,32,H,W]
{
    const int b  = blockIdx.y;
    const int px = ((blockIdx.x & 1) << 6) + (threadIdx.x & 63);
    const int py = ((blockIdx.x >> 1) << 2) + (threadIdx.x >> 6);

    int off[9]; float msk[9];
    make_taps(px, py, off, msk);

    float acc[64];
#pragma unroll
    for (int i = 0; i < 64; ++i) acc[i] = bias[i];

    const float* xb = x + (long)b * xbs;
    for (int ci = 0; ci < CINX; ++ci)
        accum<64>(xb + (long)ci * HW, off, msk, wt + (long)ci * 9 * 64, acc);

    const float* hb = h + (long)b * 32 * HW;
    for (int ci = 0; ci < 32; ++ci)
        accum<64>(hb + (long)ci * HW, off, msk, wt + (long)(CINX + ci) * 9 * 64, acc);

    const int  pix  = py * WW + px;
    const long base = (long)b * 32 * HW + pix;
#pragma unroll
    for (int co = 0; co < 32; ++co) {
        float r  = sigmoid_f(acc[co]);
        float z  = sigmoid_f(acc[co + 32]);
        float hv = hb[(long)co * HW + pix];
        rhout[base + (long)co * HW] = r * hv;
        zout [base + (long)co * HW] = z;
    }
}

// ---------------- candidate kernel: h_new = (1-z)h + z*tanh(conv) ---------
template<int CINX>
__global__ __launch_bounds__(256, 2)
void cand_kernel(const float* __restrict__ x, long xbs,
                 const float* __restrict__ rh,     // [B,32,H,W]
                 const float* __restrict__ wt,     // [(CINX+32)*9][32]
                 const float* __restrict__ bias,   // [32]
                 const float* __restrict__ z,      // [B,32,H,W]
                 float* __restrict__ hbuf)         // in/out [B,32,H,W]
{
    const int b  = blockIdx.y;
    const int px = ((blockIdx.x & 1) << 6) + (threadIdx.x & 63);
    const int py = ((blockIdx.x >> 1) << 2) + (threadIdx.x >> 6);

    int off[9]; float msk[9];
    make_taps(px, py, off, msk);

    float acc[32];
#pragma unroll
    for (int i = 0; i < 32; ++i) acc[i] = bias[i];

    const float* xb = x + (long)b * xbs;
    for (int ci = 0; ci < CINX; ++ci)
        accum<32>(xb + (long)ci * HW, off, msk, wt + (long)ci * 9 * 32, acc);

    const float* rb = rh + (long)b * 32 * HW;
    for (int ci = 0; ci < 32; ++ci)
        accum<32>(rb + (long)ci * HW, off, msk, wt + (long)(CINX + ci) * 9 * 32, acc);

    const int  pix  = py * WW + px;
    const long base = (long)b * 32 * HW + pix;
#pragma unroll
    for (int co = 0; co < 32; ++co) {
        float n  = tanh_f(acc[co]);
        long idx = base + (long)co * HW;
        float zz = z[idx];
        float hv = hbuf[idx];
        hbuf[idx] = (1.0f - zz) * hv + zz * n;
    }
}

extern "C" void kernel_launch(void* const* d_in, const int* in_sizes, int n_in,
                              void* d_out, int out_size, void* d_ws, size_t ws_size,
                              hipStream_t stream)
{
    const float* seq = (const float*)d_in[0];
    const float* gw0 = (const float*)d_in[1];
    const float* gb0 = (const float*)d_in[2];
    const float* cw0 = (const float*)d_in[3];
    const float* cb0 = (const float*)d_in[4];
    const float* gw1 = (const float*)d_in[5];
    const float* gb1 = (const float*)d_in[6];
    const float* cw1 = (const float*)d_in[7];
    const float* cb1 = (const float*)d_in[8];
    float* out = (float*)d_out;               // h1 lives here, updated in place

    const long SP = (long)BB * 32 * HW;       // 4,194,304 floats per state
    float* ws   = (float*)d_ws;
    float* h0   = ws;                         // [B,32,H,W]
    float* zb   = ws + SP;
    float* rh   = ws + 2 * SP;
    float* gwt0 = ws + 3 * SP;
    float* cwt0 = gwt0 + 64 * 33 * 9;
    float* gwt1 = cwt0 + 32 * 33 * 9;
    float* cwt1 = gwt1 + 64 * 64 * 9;

    hipMemsetAsync(h0,  0, SP * sizeof(float), stream);
    hipMemsetAsync(out, 0, SP * sizeof(float), stream);

    transpose_w<<<(64 * 33 * 9 + 255) / 256, 256, 0, stream>>>(gw0, gwt0, 64, 33);
    transpose_w<<<(32 * 33 * 9 + 255) / 256, 256, 0, stream>>>(cw0, cwt0, 32, 33);
    transpose_w<<<(64 * 64 * 9 + 255) / 256, 256, 0, stream>>>(gw1, gwt1, 64, 64);
    transpose_w<<<(32 * 64 * 9 + 255) / 256, 256, 0, stream>>>(cw1, cwt1, 32, 64);

    dim3 grid(64, BB), block(256);
    for (int t = 0; t < TT; ++t) {
        const float* xt = seq + (long)t * HW;     // [B,(T),H,W] batch stride T*HW
        gates_kernel<1 ><<<grid, block, 0, stream>>>(xt, (long)TT * HW, h0, gwt0, gb0, zb, rh);
        cand_kernel <1 ><<<grid, block, 0, stream>>>(xt, (long)TT * HW, rh, cwt0, cb0, zb, h0);
        gates_kernel<32><<<grid, block, 0, stream>>>(h0, 32L * HW, out, gwt1, gb1, zb, rh);
        cand_kernel <32><<<grid, block, 0, stream>>>(h0, 32L * HW, rh, cwt1, cb1, zb, out);
    }
}

// Round 2
// 3852.577 us; speedup vs baseline: 1.9874x; 1.9874x over previous
//
#include <hip/hip_runtime.h>
#include <hip/hip_bf16.h>

// ConvGRU via split-bf16 MFMA implicit GEMM.
// States NHWC, 1-px zero halo: S[B][130][130][64] (ch0-31=h0, ch32-63=h1),
// stored as separate hi/lo bf16 buffers. Conv = sum over K-steps of
// 16x16x32 MFMA tap-GEMMs; tap shift = pointer offset (halo => no masks).
// Precision: a*b ~= a_hi*b_hi + a_hi*b_lo + a_lo*b_hi (3 MFMAs), fp32 acc.

#define HH 128
#define PH 130
#define HW 16384
#define BB 8
#define TT 16
#define SCH 64

typedef __bf16 bf16x8 __attribute__((ext_vector_type(8)));
typedef float f32x4 __attribute__((ext_vector_type(4)));
typedef unsigned int u32x4 __attribute__((ext_vector_type(4)));

__device__ __forceinline__ unsigned short bf16_rne(float x){
    unsigned u = __float_as_uint(x);
    return (unsigned short)((u + 0x7FFFu + ((u >> 16) & 1u)) >> 16);
}
__device__ __forceinline__ float b2f(unsigned short h){
    return __uint_as_float(((unsigned)h) << 16);
}
__device__ __forceinline__ void split2(float x, unsigned short& hi, unsigned short& lo){
    hi = bf16_rne(x);
    lo = bf16_rne(x - b2f(hi));
}
__device__ __forceinline__ bf16x8 ld_frag(const unsigned short* p){
    u32x4 v = *(const u32x4*)p;
    return __builtin_bit_cast(bf16x8, v);
}
__device__ __forceinline__ float sigmoid_f(float a){ return 1.0f / (1.0f + __expf(-a)); }
__device__ __forceinline__ float tanh_f(float a){ float e2 = __expf(2.0f * a); return 1.0f - 2.0f / (e2 + 1.0f); }

// ---- weight prep: [cout][cin_tot][9] fp32 -> [step][cout][32] bf16 hi/lo ----
// step s < 9*(nhalves): tap = s%9, cin = (s/9)*32 + kk (+1 if xmode).
// xmode: last step is the im2col-x step: kk<9 -> w[co][0][kk].
__global__ void prep_w(const float* __restrict__ w, unsigned short* __restrict__ whi,
                       unsigned short* __restrict__ wlo, int CO, int CIT, int NSTEP, int xmode)
{
    int idx = blockIdx.x * 256 + threadIdx.x;
    int total = NSTEP * CO * 32;
    if (idx >= total) return;
    int kk = idx & 31;
    int t  = idx >> 5;
    int co = t % CO;
    int s  = t / CO;
    float v = 0.0f;
    if (xmode && s == NSTEP - 1) {
        if (kk < 9) v = w[(co * CIT + 0) * 9 + kk];
    } else {
        int tap = s % 9;
        int cin = (s / 9) * 32 + kk + (xmode ? 1 : 0);
        v = w[(co * CIT + cin) * 9 + tap];
    }
    unsigned short hi, lo; split2(v, hi, lo);
    whi[idx] = hi; wlo[idx] = lo;
}

// ---- X9 builder: X9[b][r][c][kk] = x[b][r+dy][c+dx] (kk<9), else 0 ----
__global__ void build_x9(const float* __restrict__ xt, long bstride,
                         unsigned short* __restrict__ xhi, unsigned short* __restrict__ xlo)
{
    int p = blockIdx.x * 256 + threadIdx.x;          // 0 .. B*HW
    int b = p >> 14, pix = p & 16383;
    int r = pix >> 7, c = pix & 127;
    const float* x = xt + (long)b * bstride;
    long base = (long)p * 32;
#pragma unroll
    for (int kk = 0; kk < 32; ++kk) {
        float v = 0.0f;
        if (kk < 9) {
            int rr = r + kk / 3 - 1, cc = c + kk % 3 - 1;
            if (rr >= 0 && rr < HH && cc >= 0 && cc < HH) v = x[rr * HH + cc];
        }
        unsigned short hi, lo; split2(v, hi, lo);
        xhi[base + kk] = hi; xlo[base + kk] = lo;
    }
}

// ---- fused conv+epilogue. CONV: 0=gates0 1=cand0 2=gates1 3=cand1 ----
template<int CONV>
__global__ __launch_bounds__(256, 2)
void conv_mfma(unsigned short* __restrict__ Shi, unsigned short* __restrict__ Slo,
               unsigned short* __restrict__ RHhi, unsigned short* __restrict__ RHlo,
               const unsigned short* __restrict__ Xhi, const unsigned short* __restrict__ Xlo,
               const unsigned short* __restrict__ Whi, const unsigned short* __restrict__ Wlo,
               const float* __restrict__ bias, float* __restrict__ zbuf)
{
    constexpr bool GATES = (CONV == 0 || CONV == 2);
    constexpr int CO    = GATES ? 64 : 32;
    constexpr int NG    = CO / 16;
    constexpr int NSTEP = (CONV < 2) ? 10 : 18;
    constexpr int HB    = (CONV < 2) ? 0 : 32;   // h channel base (h0 vs h1)

    const int b    = blockIdx.y;
    const int wid  = threadIdx.x >> 6;
    const int lane = threadIdx.x & 63;
    const int r    = ((blockIdx.x >> 1) << 2) + wid;   // image row for this wave
    const int c0   = (blockIdx.x & 1) << 6;            // col base (64 px per wave)
    const int m    = lane & 15, q = lane >> 4;

    const int PS = (b * PH + (r + 1)) * PH + (c0 + 1); // padded pixel base
    const int PX = (b * HH + r) * HH + c0;             // unpadded pixel base

    f32x4 acc[4][NG];
#pragma unroll
    for (int ng = 0; ng < NG; ++ng) {
        float bv = bias[ng * 16 + m];
#pragma unroll
        for (int mg = 0; mg < 4; ++mg) acc[mg][ng] = f32x4{bv, bv, bv, bv};
    }

#pragma unroll
    for (int s = 0; s < NSTEP; ++s) {
        bf16x8 Ahi[4], Alo[4], Bhi[NG], Blo[NG];

        bool isx = (CONV < 2) && (s == 9);
        if (isx) {
            int p0 = PX + m;
#pragma unroll
            for (int mg = 0; mg < 4; ++mg) {
                int idx = (p0 + mg * 16) * 32 + q * 8;
                Ahi[mg] = ld_frag(Xhi + idx);
                Alo[mg] = ld_frag(Xlo + idx);
            }
        } else {
            const unsigned short *ahi, *alo;
            int pch, choff;
            int tap = (s < 9) ? s : s - 9;
            if (CONV == 0 || CONV == 2) { ahi = Shi; alo = Slo; pch = SCH; choff = 0; }
            if (CONV == 1)              { ahi = RHhi; alo = RHlo; pch = 32; choff = 0; }
            if (CONV == 2 && s >= 9)    { choff = 32; }
            if (CONV == 3) {
                if (s < 9) { ahi = Shi; alo = Slo; pch = SCH; choff = 0; }
                else       { ahi = RHhi; alo = RHlo; pch = 32; choff = 0; }
            }
            int shift = (tap / 3 - 1) * PH + (tap % 3 - 1);
            int p0 = PS + shift + m;
#pragma unroll
            for (int mg = 0; mg < 4; ++mg) {
                int idx = (p0 + mg * 16) * pch + choff + q * 8;
                Ahi[mg] = ld_frag(ahi + idx);
                Alo[mg] = ld_frag(alo + idx);
            }
        }
#pragma unroll
        for (int ng = 0; ng < NG; ++ng) {
            int widx = (s * CO + ng * 16 + m) * 32 + q * 8;
            Bhi[ng] = ld_frag(Whi + widx);
            Blo[ng] = ld_frag(Wlo + widx);
        }
#pragma unroll
        for (int mg = 0; mg < 4; ++mg)
#pragma unroll
            for (int ng = 0; ng < NG; ++ng) {
                acc[mg][ng] = __builtin_amdgcn_mfma_f32_16x16x32_bf16(Ahi[mg], Bhi[ng], acc[mg][ng], 0, 0, 0);
                acc[mg][ng] = __builtin_amdgcn_mfma_f32_16x16x32_bf16(Ahi[mg], Blo[ng], acc[mg][ng], 0, 0, 0);
                acc[mg][ng] = __builtin_amdgcn_mfma_f32_16x16x32_bf16(Alo[mg], Bhi[ng], acc[mg][ng], 0, 0, 0);
            }
    }

    // ---- epilogue. C layout: col(n)=lane&15, row(pixel)=q*4+reg ----
    if (GATES) {
#pragma unroll
        for (int mg = 0; mg < 4; ++mg)
#pragma unroll
            for (int ng = 0; ng < 2; ++ng)
#pragma unroll
                for (int rg = 0; rg < 4; ++rg) {
                    int po = mg * 16 + q * 4 + rg;       // pixel offset within 64
                    int n  = ng * 16 + m;                // cout 0..31
                    float rgate = sigmoid_f(acc[mg][ng][rg]);
                    float zgate = sigmoid_f(acc[mg][ng + 2][rg]);
                    int sidx = (PS + po) * SCH + HB + n;
                    float h = b2f(Shi[sidx]) + b2f(Slo[sidx]);
                    float rh = rgate * h;
                    unsigned short hi, lo; split2(rh, hi, lo);
                    int rhidx = (PS + po) * 32 + n;
                    RHhi[rhidx] = hi; RHlo[rhidx] = lo;
                    zbuf[(PX + po) * 32 + n] = zgate;
                }
    } else {
#pragma unroll
        for (int mg = 0; mg < 4; ++mg)
#pragma unroll
            for (int ng = 0; ng < 2; ++ng)
#pragma unroll
                for (int rg = 0; rg < 4; ++rg) {
                    int po = mg * 16 + q * 4 + rg;
                    int n  = ng * 16 + m;
                    float nv = tanh_f(acc[mg][ng][rg]);
                    float zz = zbuf[(PX + po) * 32 + n];
                    int sidx = (PS + po) * SCH + HB + n;
                    float h = b2f(Shi[sidx]) + b2f(Slo[sidx]);
                    float hn = (1.0f - zz) * h + zz * nv;
                    unsigned short hi, lo; split2(hn, hi, lo);
                    Shi[sidx] = hi; Slo[sidx] = lo;
                }
    }
}

// ---- final: S ch32-63 (h1) -> d_out NCHW fp32 ----
__global__ void final_out(const unsigned short* __restrict__ Shi,
                          const unsigned short* __restrict__ Slo, float* __restrict__ out)
{
    int i = blockIdx.x * 256 + threadIdx.x;    // B*32*HW = 4194304
    if (i >= BB * 32 * HW) return;
    int pix = i & 16383;
    int t = i >> 14;
    int c = t & 31, b = t >> 5;
    int r = pix >> 7, cc = pix & 127;
    int ps = (b * PH + r + 1) * PH + cc + 1;
    out[i] = b2f(Shi[ps * SCH + 32 + c]) + b2f(Slo[ps * SCH + 32 + c]);
}

extern "C" void kernel_launch(void* const* d_in, const int* in_sizes, int n_in,
                              void* d_out, int out_size, void* d_ws, size_t ws_size,
                              hipStream_t stream)
{
    const float* seq = (const float*)d_in[0];
    const float* gw0 = (const float*)d_in[1];
    const float* gb0 = (const float*)d_in[2];
    const float* cw0 = (const float*)d_in[3];
    const float* cb0 = (const float*)d_in[4];
    const float* gw1 = (const float*)d_in[5];
    const float* gb1 = (const float*)d_in[6];
    const float* cw1 = (const float*)d_in[7];
    const float* cb1 = (const float*)d_in[8];
    float* out = (float*)d_out;

    const size_t NS  = (size_t)BB * PH * PH * SCH;   // 8,652,800
    const size_t NRH = (size_t)BB * PH * PH * 32;    // 4,326,400
    const size_t NX  = (size_t)BB * HH * HH * 32;    // 4,194,304
    const size_t NZ  = NX;

    char* p = (char*)d_ws;
    unsigned short* Shi  = (unsigned short*)p; p += NS  * 2;
    unsigned short* Slo  = (unsigned short*)p; p += NS  * 2;
    unsigned short* RHhi = (unsigned short*)p; p += NRH * 2;
    unsigned short* RHlo = (unsigned short*)p; p += NRH * 2;
    unsigned short* Xhi  = (unsigned short*)p; p += NX  * 2;
    unsigned short* Xlo  = (unsigned short*)p; p += NX  * 2;
    float* zbuf          = (float*)p;          p += NZ  * 4;
    unsigned short* WG0h = (unsigned short*)p; p += 20480 * 2;
    unsigned short* WG0l = (unsigned short*)p; p += 20480 * 2;
    unsigned short* WC0h = (unsigned short*)p; p += 10240 * 2;
    unsigned short* WC0l = (unsigned short*)p; p += 10240 * 2;
    unsigned short* WG1h = (unsigned short*)p; p += 36864 * 2;
    unsigned short* WG1l = (unsigned short*)p; p += 36864 * 2;
    unsigned short* WC1h = (unsigned short*)p; p += 18432 * 2;
    unsigned short* WC1l = (unsigned short*)p; p += 18432 * 2;

    // zero S (states start at 0; halo stays 0) and RH halo, in one contiguous span
    hipMemsetAsync(Shi, 0, (2 * NS + 2 * NRH) * 2, stream);

    prep_w<<<(10 * 64 * 32 + 255) / 256, 256, 0, stream>>>(gw0, WG0h, WG0l, 64, 33, 10, 1);
    prep_w<<<(10 * 32 * 32 + 255) / 256, 256, 0, stream>>>(cw0, WC0h, WC0l, 32, 33, 10, 1);
    prep_w<<<(18 * 64 * 32 + 255) / 256, 256, 0, stream>>>(gw1, WG1h, WG1l, 64, 64, 18, 0);
    prep_w<<<(18 * 32 * 32 + 255) / 256, 256, 0, stream>>>(cw1, WC1h, WC1l, 32, 64, 18, 0);

    dim3 grid(64, BB), block(256);
    for (int t = 0; t < TT; ++t) {
        build_x9<<<(BB * HW + 255) / 256, 256, 0, stream>>>(seq + (long)t * HW, (long)TT * HW, Xhi, Xlo);
        conv_mfma<0><<<grid, block, 0, stream>>>(Shi, Slo, RHhi, RHlo, Xhi, Xlo, WG0h, WG0l, gb0, zbuf);
        conv_mfma<1><<<grid, block, 0, stream>>>(Shi, Slo, RHhi, RHlo, Xhi, Xlo, WC0h, WC0l, cb0, zbuf);
        conv_mfma<2><<<grid, block, 0, stream>>>(Shi, Slo, RHhi, RHlo, Xhi, Xlo, WG1h, WG1l, gb1, zbuf);
        conv_mfma<3><<<grid, block, 0, stream>>>(Shi, Slo, RHhi, RHlo, Xhi, Xlo, WC1h, WC1l, cb1, zbuf);
    }
    final_out<<<(BB * 32 * HW + 255) / 256, 256, 0, stream>>>(Shi, Slo, out);
}

// Round 3
// 2867.122 us; speedup vs baseline: 2.6705x; 1.3437x over previous
//
#include <hip/hip_runtime.h>
#include <hip/hip_bf16.h>

// ConvGRU via split-bf16 MFMA implicit GEMM with LDS tap staging.
// States NHWC, 1-px zero halo: S[B][130][130][64] (ch0-31=h0, ch32-63=h1),
// separate hi/lo bf16 buffers. Each WG stages its input plane tile (6x34
// halo) into LDS once; the 9 tap-shifted A-fragments are ds_read_b128 from
// LDS in a q-blocked conflict-free layout [4][6][34][8].
// Precision: a*b ~= a_hi*b_hi + a_hi*b_lo + a_lo*b_hi (3 MFMAs), fp32 acc.

#define HH 128
#define PH 130
#define HW 16384
#define BB 8
#define TT 16

typedef __bf16 bf16x8 __attribute__((ext_vector_type(8)));
typedef float f32x4 __attribute__((ext_vector_type(4)));
typedef unsigned int u32x4 __attribute__((ext_vector_type(4)));

#define SLOT_SZ (4 * 6 * 34 * 8)   // 6528 ushorts = 13056 B

__device__ __forceinline__ unsigned short bf16_rne(float x){
    unsigned u = __float_as_uint(x);
    return (unsigned short)((u + 0x7FFFu + ((u >> 16) & 1u)) >> 16);
}
__device__ __forceinline__ float b2f(unsigned short h){
    return __uint_as_float(((unsigned)h) << 16);
}
__device__ __forceinline__ __bf16 us2bf(unsigned short u){
    return __builtin_bit_cast(__bf16, u);
}
__device__ __forceinline__ void split2(float x, unsigned short& hi, unsigned short& lo){
    hi = bf16_rne(x);
    lo = bf16_rne(x - b2f(hi));
}
__device__ __forceinline__ bf16x8 ld_frag(const unsigned short* p){
    u32x4 v = *(const u32x4*)p;
    return __builtin_bit_cast(bf16x8, v);
}
__device__ __forceinline__ bf16x8 lds_frag(const unsigned short* slot, int q, int row, int col){
    u32x4 v = *(const u32x4*)(slot + ((q * 6 + row) * 34 + col) * 8);
    return __builtin_bit_cast(bf16x8, v);
}
__device__ __forceinline__ float sigmoid_f(float a){ return 1.0f / (1.0f + __expf(-a)); }
__device__ __forceinline__ float tanh_f(float a){ float e2 = __expf(2.0f * a); return 1.0f - 2.0f / (e2 + 1.0f); }

// stage one 32-ch plane-half tile (6 rows x 34 cols) into an LDS slot.
// LDS slot layout: [qblk 4][row 6][col 34][8ch].
__device__ __forceinline__ void stage_slot(unsigned short* lds_slot,
    const unsigned short* __restrict__ g, int pch, int choff, int pbase)
{
    for (int c = threadIdx.x; c < 816; c += 256) {
        int qq = c & 3;
        int p  = c >> 2;
        int r  = p / 34, cc = p - r * 34;
        const unsigned short* ga = g + (long)(pbase + r * PH + cc) * pch + choff + qq * 8;
        u32x4 v = *(const u32x4*)ga;
        *(u32x4*)(lds_slot + ((qq * 6 + r) * 34 + cc) * 8) = v;
    }
}

// stage raw x (unpadded fp32 image) tile with bounds-check into LDS
__device__ __forceinline__ void stage_x(float* xt, const float* __restrict__ x,
                                        int row0p, int col0p)
{
    for (int p = threadIdx.x; p < 204; p += 256) {
        int r = p / 34, cc = p - r * 34;
        int ir = row0p - 1 + r, ic = col0p - 1 + cc;
        float v = 0.0f;
        if (ir >= 0 && ir < HH && ic >= 0 && ic < HH) v = x[ir * HH + ic];
        xt[r * 34 + cc] = v;
    }
}

// ---- weight prep: [cout][cin_tot][9] fp32 -> [step][cout][32] bf16 hi/lo ----
__global__ void prep_w(const float* __restrict__ w, unsigned short* __restrict__ whi,
                       unsigned short* __restrict__ wlo, int CO, int CIT, int NSTEP, int xmode)
{
    int idx = blockIdx.x * 256 + threadIdx.x;
    int total = NSTEP * CO * 32;
    if (idx >= total) return;
    int kk = idx & 31;
    int t  = idx >> 5;
    int co = t % CO;
    int s  = t / CO;
    float v = 0.0f;
    if (xmode && s == NSTEP - 1) {
        if (kk < 9) v = w[(co * CIT + 0) * 9 + kk];
    } else {
        int tap = s % 9;
        int cin = (s / 9) * 32 + kk + (xmode ? 1 : 0);
        v = w[(co * CIT + cin) * 9 + tap];
    }
    unsigned short hi, lo; split2(v, hi, lo);
    whi[idx] = hi; wlo[idx] = lo;
}

// ---- fused conv+epilogue. CONV: 0=gates0 1=cand0 2=gates1 3=cand1 ----
// WG = 256 thr (4 waves), tile 4 rows x 32 cols. wave wv = row, 2 m-tiles.
template<int CONV>
__global__ __launch_bounds__(256, 3)
void conv_mfma(unsigned short* __restrict__ Shi, unsigned short* __restrict__ Slo,
               unsigned short* __restrict__ RHhi, unsigned short* __restrict__ RHlo,
               const float* __restrict__ xraw, long xbs,
               const unsigned short* __restrict__ Whi, const unsigned short* __restrict__ Wlo,
               const float* __restrict__ bias, float* __restrict__ zbuf)
{
    constexpr bool GATES = (CONV == 0 || CONV == 2);
    constexpr int CO    = GATES ? 64 : 32;
    constexpr int NG    = CO / 16;
    constexpr int NSTEP = (CONV < 2) ? 10 : 18;
    constexpr int NSLOT = (CONV < 2) ? 2 : 4;
    constexpr int HB    = (CONV < 2) ? 0 : 32;   // h channel base (h0 vs h1)
    constexpr bool XMODE = (CONV < 2);

    __shared__ __align__(16) unsigned short lds[NSLOT][SLOT_SZ];
    __shared__ float xt[XMODE ? 204 : 1];

    const int b   = blockIdx.y;
    const int tc  = blockIdx.x & 3;     // 0..3   (32-col tiles)
    const int tr  = blockIdx.x >> 2;    // 0..31  (4-row tiles)
    const int row0p = tr * 4;           // halo origin, padded coords
    const int col0p = tc * 32;
    const int pbase = (b * PH + row0p) * PH + col0p;

    if (CONV == 0) {
        stage_slot(lds[0], Shi, 64, 0, pbase);
        stage_slot(lds[1], Slo, 64, 0, pbase);
    } else if (CONV == 1) {
        stage_slot(lds[0], RHhi, 32, 0, pbase);
        stage_slot(lds[1], RHlo, 32, 0, pbase);
    } else if (CONV == 2) {
        stage_slot(lds[0], Shi, 64, 0,  pbase);
        stage_slot(lds[1], Slo, 64, 0,  pbase);
        stage_slot(lds[2], Shi, 64, 32, pbase);
        stage_slot(lds[3], Slo, 64, 32, pbase);
    } else {
        stage_slot(lds[0], Shi, 64, 0, pbase);
        stage_slot(lds[1], Slo, 64, 0, pbase);
        stage_slot(lds[2], RHhi, 32, 0, pbase);
        stage_slot(lds[3], RHlo, 32, 0, pbase);
    }
    if (XMODE) stage_x(xt, xraw + (long)b * xbs, row0p, col0p);
    __syncthreads();

    const int wv   = threadIdx.x >> 6;
    const int lane = threadIdx.x & 63;
    const int m    = lane & 15, q = lane >> 4;

    f32x4 acc[2][NG];
#pragma unroll
    for (int ng = 0; ng < NG; ++ng) {
        float bv = bias[ng * 16 + m];
#pragma unroll
        for (int mg = 0; mg < 2; ++mg) acc[mg][ng] = f32x4{bv, bv, bv, bv};
    }

#pragma unroll
    for (int s = 0; s < NSTEP; ++s) {
        bf16x8 Ahi[2], Alo[2], Bh[NG], Bl[NG];

        if (XMODE && s == 9) {
#pragma unroll
            for (int mg = 0; mg < 2; ++mg) {
                bf16x8 vh, vl;
#pragma unroll
                for (int j = 0; j < 8; ++j) {
                    int k = q * 8 + j;
                    float v = 0.0f;
                    if (k < 9) v = xt[(wv + k / 3) * 34 + (mg * 16 + m + k % 3)];
                    unsigned short hi, lo; split2(v, hi, lo);
                    vh[j] = us2bf(hi); vl[j] = us2bf(lo);
                }
                Ahi[mg] = vh; Alo[mg] = vl;
            }
        } else {
            const int pair = (s < 9) ? 0 : 2;
            const int tap  = (s < 9) ? s : s - 9;
            const int rr   = wv + tap / 3;
            const int csh  = tap % 3;
#pragma unroll
            for (int mg = 0; mg < 2; ++mg) {
                Ahi[mg] = lds_frag(lds[pair],     q, rr, mg * 16 + m + csh);
                Alo[mg] = lds_frag(lds[pair + 1], q, rr, mg * 16 + m + csh);
            }
        }
#pragma unroll
        for (int ng = 0; ng < NG; ++ng) {
            int widx = (s * CO + ng * 16 + m) * 32 + q * 8;
            Bh[ng] = ld_frag(Whi + widx);
            Bl[ng] = ld_frag(Wlo + widx);
        }
#pragma unroll
        for (int mg = 0; mg < 2; ++mg)
#pragma unroll
            for (int ng = 0; ng < NG; ++ng) {
                acc[mg][ng] = __builtin_amdgcn_mfma_f32_16x16x32_bf16(Ahi[mg], Bh[ng], acc[mg][ng], 0, 0, 0);
                acc[mg][ng] = __builtin_amdgcn_mfma_f32_16x16x32_bf16(Ahi[mg], Bl[ng], acc[mg][ng], 0, 0, 0);
                acc[mg][ng] = __builtin_amdgcn_mfma_f32_16x16x32_bf16(Alo[mg], Bh[ng], acc[mg][ng], 0, 0, 0);
            }
    }

    // ---- epilogue. C layout: col(n)=lane&15, row(pixel)=q*4+reg ----
    const int prow = row0p + wv;   // image row of this wave's pixels
    if (GATES) {
        constexpr int HSLOT = (CONV == 0) ? 0 : 2;
#pragma unroll
        for (int mg = 0; mg < 2; ++mg)
#pragma unroll
            for (int ng = 0; ng < NG / 2; ++ng)
#pragma unroll
                for (int rg = 0; rg < 4; ++rg) {
                    int lcol = mg * 16 + q * 4 + rg;               // 0..31
                    int psp  = (b * PH + prow + 1) * PH + (col0p + 1 + lcol);
                    int pxp  = (b * HH + prow) * HH + (col0p + lcol);
                    int n    = ng * 16 + m;
                    float rgate = sigmoid_f(acc[mg][ng][rg]);
                    float zgate = sigmoid_f(acc[mg][ng + NG / 2][rg]);
                    int laddr = (((n >> 3) * 6 + (wv + 1)) * 34 + (1 + lcol)) * 8 + (n & 7);
                    float h = b2f(lds[HSLOT][laddr]) + b2f(lds[HSLOT + 1][laddr]);
                    float rh = rgate * h;
                    unsigned short hi, lo; split2(rh, hi, lo);
                    RHhi[psp * 32 + n] = hi;
                    RHlo[psp * 32 + n] = lo;
                    zbuf[(long)pxp * 32 + n] = zgate;
                }
    } else {
#pragma unroll
        for (int mg = 0; mg < 2; ++mg)
#pragma unroll
            for (int ng = 0; ng < NG; ++ng)
#pragma unroll
                for (int rg = 0; rg < 4; ++rg) {
                    int lcol = mg * 16 + q * 4 + rg;
                    int psp  = (b * PH + prow + 1) * PH + (col0p + 1 + lcol);
                    int pxp  = (b * HH + prow) * HH + (col0p + lcol);
                    int n    = ng * 16 + m;
                    float nv = tanh_f(acc[mg][ng][rg]);
                    float zz = zbuf[(long)pxp * 32 + n];
                    int sidx = psp * 64 + HB + n;
                    float h = b2f(Shi[sidx]) + b2f(Slo[sidx]);
                    float hn = (1.0f - zz) * h + zz * nv;
                    unsigned short hi, lo; split2(hn, hi, lo);
                    Shi[sidx] = hi; Slo[sidx] = lo;
                }
    }
}

// ---- final: S ch32-63 (h1) -> d_out NCHW fp32 ----
__global__ void final_out(const unsigned short* __restrict__ Shi,
                          const unsigned short* __restrict__ Slo, float* __restrict__ out)
{
    int i = blockIdx.x * 256 + threadIdx.x;    // B*32*HW = 4194304
    if (i >= BB * 32 * HW) return;
    int pix = i & 16383;
    int t = i >> 14;
    int c = t & 31, b = t >> 5;
    int r = pix >> 7, cc = pix & 127;
    int ps = (b * PH + r + 1) * PH + cc + 1;
    out[i] = b2f(Shi[ps * 64 + 32 + c]) + b2f(Slo[ps * 64 + 32 + c]);
}

extern "C" void kernel_launch(void* const* d_in, const int* in_sizes, int n_in,
                              void* d_out, int out_size, void* d_ws, size_t ws_size,
                              hipStream_t stream)
{
    const float* seq = (const float*)d_in[0];
    const float* gw0 = (const float*)d_in[1];
    const float* gb0 = (const float*)d_in[2];
    const float* cw0 = (const float*)d_in[3];
    const float* cb0 = (const float*)d_in[4];
    const float* gw1 = (const float*)d_in[5];
    const float* gb1 = (const float*)d_in[6];
    const float* cw1 = (const float*)d_in[7];
    const float* cb1 = (const float*)d_in[8];
    float* out = (float*)d_out;

    const size_t NS  = (size_t)BB * PH * PH * 64;    // 8,652,800
    const size_t NRH = (size_t)BB * PH * PH * 32;    // 4,326,400
    const size_t NZ  = (size_t)BB * HH * HH * 32;    // 4,194,304

    char* p = (char*)d_ws;
    unsigned short* Shi  = (unsigned short*)p; p += NS  * 2;
    unsigned short* Slo  = (unsigned short*)p; p += NS  * 2;
    unsigned short* RHhi = (unsigned short*)p; p += NRH * 2;
    unsigned short* RHlo = (unsigned short*)p; p += NRH * 2;
    float* zbuf          = (float*)p;          p += NZ  * 4;
    unsigned short* WG0h = (unsigned short*)p; p += 20480 * 2;
    unsigned short* WG0l = (unsigned short*)p; p += 20480 * 2;
    unsigned short* WC0h = (unsigned short*)p; p += 10240 * 2;
    unsigned short* WC0l = (unsigned short*)p; p += 10240 * 2;
    unsigned short* WG1h = (unsigned short*)p; p += 36864 * 2;
    unsigned short* WG1l = (unsigned short*)p; p += 36864 * 2;
    unsigned short* WC1h = (unsigned short*)p; p += 18432 * 2;
    unsigned short* WC1l = (unsigned short*)p; p += 18432 * 2;

    // zero S (states + halo) and RH (halo), one contiguous span
    hipMemsetAsync(Shi, 0, (2 * NS + 2 * NRH) * 2, stream);

    prep_w<<<(10 * 64 * 32 + 255) / 256, 256, 0, stream>>>(gw0, WG0h, WG0l, 64, 33, 10, 1);
    prep_w<<<(10 * 32 * 32 + 255) / 256, 256, 0, stream>>>(cw0, WC0h, WC0l, 32, 33, 10, 1);
    prep_w<<<(18 * 64 * 32 + 255) / 256, 256, 0, stream>>>(gw1, WG1h, WG1l, 64, 64, 18, 0);
    prep_w<<<(18 * 32 * 32 + 255) / 256, 256, 0, stream>>>(cw1, WC1h, WC1l, 32, 64, 18, 0);

    dim3 grid(128, BB), block(256);
    const long xbs = (long)TT * HW;
    for (int t = 0; t < TT; ++t) {
        const float* xt = seq + (long)t * HW;
        conv_mfma<0><<<grid, block, 0, stream>>>(Shi, Slo, RHhi, RHlo, xt, xbs, WG0h, WG0l, gb0, zbuf);
        conv_mfma<1><<<grid, block, 0, stream>>>(Shi, Slo, RHhi, RHlo, xt, xbs, WC0h, WC0l, cb0, zbuf);
        conv_mfma<2><<<grid, block, 0, stream>>>(Shi, Slo, RHhi, RHlo, xt, xbs, WG1h, WG1l, gb1, zbuf);
        conv_mfma<3><<<grid, block, 0, stream>>>(Shi, Slo, RHhi, RHlo, xt, xbs, WC1h, WC1l, cb1, zbuf);
    }
    final_out<<<(BB * 32 * HW + 255) / 256, 256, 0, stream>>>(Shi, Slo, out);
}

// Round 4
// 2116.742 us; speedup vs baseline: 3.6171x; 1.3545x over previous
//
#include <hip/hip_runtime.h>
#include <hip/hip_bf16.h>

// ConvGRU via split-bf16 MFMA implicit GEMM, LDS tap staging, phase-split
// K-loop (one 32-ch plane in LDS at a time -> 27.7KB -> all WGs co-resident).
// States packed u32 = (hi_bf16<<16)|lo_bf16, NHWC, 1-px halo:
//   Sp[B][130][130][64] (ch0-31=h0, ch32-63=h1), RHp[B][130][130][32].
// Precision: a*b ~= a_hi*b_hi + a_hi*b_lo + a_lo*b_hi (3 MFMAs), fp32 acc.

#define HH 128
#define PH 130
#define HW 16384
#define BB 8
#define TT 16

typedef __bf16 bf16x8 __attribute__((ext_vector_type(8)));
typedef float f32x4 __attribute__((ext_vector_type(4)));
typedef unsigned int u32x4 __attribute__((ext_vector_type(4)));

#define SLOT_SZ (4 * 6 * 35 * 8)   // 6720 ushorts = 13440 B (col stride 35: pad)

__device__ __forceinline__ unsigned short bf16_rne(float x){
    unsigned u = __float_as_uint(x);
    return (unsigned short)((u + 0x7FFFu + ((u >> 16) & 1u)) >> 16);
}
__device__ __forceinline__ float b2f(unsigned short h){
    return __uint_as_float(((unsigned)h) << 16);
}
__device__ __forceinline__ __bf16 us2bf(unsigned short u){
    return __builtin_bit_cast(__bf16, u);
}
__device__ __forceinline__ void split2(float x, unsigned short& hi, unsigned short& lo){
    hi = bf16_rne(x);
    lo = bf16_rne(x - b2f(hi));
}
__device__ __forceinline__ unsigned packsplit(float x){
    unsigned short hi, lo; split2(x, hi, lo);
    return ((unsigned)hi << 16) | lo;
}
__device__ __forceinline__ float unpack2f(unsigned w){
    return b2f((unsigned short)(w >> 16)) + b2f((unsigned short)(w & 0xffffu));
}
__device__ __forceinline__ bf16x8 ld_frag(const unsigned short* p){
    u32x4 v = *(const u32x4*)p;
    return __builtin_bit_cast(bf16x8, v);
}
__device__ __forceinline__ bf16x8 lds_frag(const unsigned short* slot, int q, int row, int col){
    u32x4 v = *(const u32x4*)(slot + ((q * 6 + row) * 35 + col) * 8);
    return __builtin_bit_cast(bf16x8, v);
}
__device__ __forceinline__ float sigmoid_f(float a){ return 1.0f / (1.0f + __expf(-a)); }
__device__ __forceinline__ float tanh_f(float a){ float e2 = __expf(2.0f * a); return 1.0f - 2.0f / (e2 + 1.0f); }

// stage one packed 32-ch plane tile (6 rows x 34 cols) into hi/lo LDS slots.
// LDS slot layout: [qblk 4][row 6][col 35(pad)][8ch].
__device__ __forceinline__ void stage_pair(unsigned short* hs, unsigned short* ls,
    const unsigned int* __restrict__ g, int pch, int choff, int pbase)
{
    for (int c = threadIdx.x; c < 816; c += 256) {
        int qq = c & 3;
        int p  = c >> 2;
        int r  = p / 34, cc = p - r * 34;
        const unsigned int* ga = g + (long)(pbase + r * PH + cc) * pch + choff + qq * 8;
        u32x4 w0 = *(const u32x4*)ga;
        u32x4 w1 = *(const u32x4*)(ga + 4);
        u32x4 hv, lv;
        hv[0] = (w0[0] >> 16) | (w0[1] & 0xffff0000u);
        hv[1] = (w0[2] >> 16) | (w0[3] & 0xffff0000u);
        hv[2] = (w1[0] >> 16) | (w1[1] & 0xffff0000u);
        hv[3] = (w1[2] >> 16) | (w1[3] & 0xffff0000u);
        lv[0] = (w0[0] & 0xffffu) | (w0[1] << 16);
        lv[1] = (w0[2] & 0xffffu) | (w0[3] << 16);
        lv[2] = (w1[0] & 0xffffu) | (w1[1] << 16);
        lv[3] = (w1[2] & 0xffffu) | (w1[3] << 16);
        int la = ((qq * 6 + r) * 35 + cc) * 8;
        *(u32x4*)(hs + la) = hv;
        *(u32x4*)(ls + la) = lv;
    }
}

// stage raw x (unpadded fp32 image) tile with bounds-check into LDS
__device__ __forceinline__ void stage_x(float* xt, const float* __restrict__ x,
                                        int row0p, int col0p)
{
    for (int p = threadIdx.x; p < 204; p += 256) {
        int r = p / 34, cc = p - r * 34;
        int ir = row0p - 1 + r, ic = col0p - 1 + cc;
        float v = 0.0f;
        if (ir >= 0 && ir < HH && ic >= 0 && ic < HH) v = x[ir * HH + ic];
        xt[r * 35 + cc] = v;
    }
}

// ---- weight prep: [cout][cin_tot][9] fp32 -> [step][cout][32] bf16 hi/lo ----
__global__ void prep_w(const float* __restrict__ w, unsigned short* __restrict__ whi,
                       unsigned short* __restrict__ wlo, int CO, int CIT, int NSTEP, int xmode)
{
    int idx = blockIdx.x * 256 + threadIdx.x;
    int total = NSTEP * CO * 32;
    if (idx >= total) return;
    int kk = idx & 31;
    int t  = idx >> 5;
    int co = t % CO;
    int s  = t / CO;
    float v = 0.0f;
    if (xmode && s == NSTEP - 1) {
        if (kk < 9) v = w[(co * CIT + 0) * 9 + kk];
    } else {
        int tap = s % 9;
        int cin = (s / 9) * 32 + kk + (xmode ? 1 : 0);
        v = w[(co * CIT + cin) * 9 + tap];
    }
    unsigned short hi, lo; split2(v, hi, lo);
    whi[idx] = hi; wlo[idx] = lo;
}

// ---- fused conv+epilogue. CONV: 0=gates0 1=cand0 2=gates1 3=cand1 ----
// WG = 256 thr (4 waves), tile 4 rows x 32 cols; wave = one row, 2 m-tiles.
template<int CONV>
__global__ __launch_bounds__(256, 4)
void conv_mfma(unsigned int* __restrict__ Sp, unsigned int* __restrict__ RHp,
               const float* __restrict__ xraw, long xbs,
               const unsigned short* __restrict__ Whi, const unsigned short* __restrict__ Wlo,
               const float* __restrict__ bias, float* __restrict__ zbuf)
{
    constexpr bool GATES = (CONV == 0 || CONV == 2);
    constexpr bool XMODE = (CONV < 2);
    constexpr int CO = GATES ? 64 : 32;
    constexpr int NG = CO / 16;
    constexpr int HB = XMODE ? 0 : 32;   // h channel base in Sp (h0 vs h1)

    __shared__ __align__(16) unsigned short sh[SLOT_SZ], sl[SLOT_SZ];
    __shared__ float xt[XMODE ? 210 : 1];

    const int b   = blockIdx.y;
    const int tc  = blockIdx.x & 3;     // 0..3   (32-col tiles)
    const int tr  = blockIdx.x >> 2;    // 0..31  (4-row tiles)
    const int row0p = tr * 4;           // halo origin, padded coords
    const int col0p = tc * 32;
    const int pbase = (b * PH + row0p) * PH + col0p;

    // phase A staging: conv0/2/3 -> S h0-half; conv1 -> RH
    if (CONV == 1) stage_pair(sh, sl, RHp, 32, 0, pbase);
    else           stage_pair(sh, sl, Sp, 64, 0, pbase);
    if (XMODE) stage_x(xt, xraw + (long)b * xbs, row0p, col0p);
    __syncthreads();

    const int wv   = threadIdx.x >> 6;
    const int lane = threadIdx.x & 63;
    const int m    = lane & 15, q = lane >> 4;

    f32x4 acc[2][NG];
#pragma unroll
    for (int ng = 0; ng < NG; ++ng) {
        float bv = bias[ng * 16 + m];
#pragma unroll
        for (int mg = 0; mg < 2; ++mg) acc[mg][ng] = f32x4{bv, bv, bv, bv};
    }

#define KSTEP(S, TAP)                                                           \
    {                                                                           \
        bf16x8 Ahi[2], Alo[2], Bh[NG], Bl[NG];                                  \
        const int rr = wv + (TAP) / 3, csh = (TAP) % 3;                         \
        _Pragma("unroll")                                                       \
        for (int mg = 0; mg < 2; ++mg) {                                        \
            Ahi[mg] = lds_frag(sh, q, rr, mg * 16 + m + csh);                   \
            Alo[mg] = lds_frag(sl, q, rr, mg * 16 + m + csh);                   \
        }                                                                       \
        _Pragma("unroll")                                                       \
        for (int ng = 0; ng < NG; ++ng) {                                       \
            int widx = ((S) * CO + ng * 16 + m) * 32 + q * 8;                   \
            Bh[ng] = ld_frag(Whi + widx);                                       \
            Bl[ng] = ld_frag(Wlo + widx);                                       \
        }                                                                       \
        _Pragma("unroll")                                                       \
        for (int mg = 0; mg < 2; ++mg)                                          \
            _Pragma("unroll")                                                   \
            for (int ng = 0; ng < NG; ++ng) {                                   \
                acc[mg][ng] = __builtin_amdgcn_mfma_f32_16x16x32_bf16(Ahi[mg], Bh[ng], acc[mg][ng], 0, 0, 0); \
                acc[mg][ng] = __builtin_amdgcn_mfma_f32_16x16x32_bf16(Ahi[mg], Bl[ng], acc[mg][ng], 0, 0, 0); \
                acc[mg][ng] = __builtin_amdgcn_mfma_f32_16x16x32_bf16(Alo[mg], Bh[ng], acc[mg][ng], 0, 0, 0); \
            }                                                                   \
    }

#pragma unroll
    for (int s = 0; s < 9; ++s) KSTEP(s, s)

    if (XMODE) {
        // im2col x step (s=9): A[m][k] = x tap k (k<9), else 0
        bf16x8 Bh[NG], Bl[NG];
        bf16x8 Ahi[2], Alo[2];
#pragma unroll
        for (int mg = 0; mg < 2; ++mg) {
            bf16x8 vh, vl;
#pragma unroll
            for (int j = 0; j < 8; ++j) {
                int k = q * 8 + j;
                float v = 0.0f;
                if (k < 9) v = xt[(wv + k / 3) * 35 + (mg * 16 + m + k % 3)];
                unsigned short hi, lo; split2(v, hi, lo);
                vh[j] = us2bf(hi); vl[j] = us2bf(lo);
            }
            Ahi[mg] = vh; Alo[mg] = vl;
        }
#pragma unroll
        for (int ng = 0; ng < NG; ++ng) {
            int widx = (9 * CO + ng * 16 + m) * 32 + q * 8;
            Bh[ng] = ld_frag(Whi + widx);
            Bl[ng] = ld_frag(Wlo + widx);
        }
#pragma unroll
        for (int mg = 0; mg < 2; ++mg)
#pragma unroll
            for (int ng = 0; ng < NG; ++ng) {
                acc[mg][ng] = __builtin_amdgcn_mfma_f32_16x16x32_bf16(Ahi[mg], Bh[ng], acc[mg][ng], 0, 0, 0);
                acc[mg][ng] = __builtin_amdgcn_mfma_f32_16x16x32_bf16(Ahi[mg], Bl[ng], acc[mg][ng], 0, 0, 0);
                acc[mg][ng] = __builtin_amdgcn_mfma_f32_16x16x32_bf16(Alo[mg], Bh[ng], acc[mg][ng], 0, 0, 0);
            }
    } else {
        // phase B: conv2 -> S h1-half; conv3 -> RH. Re-stage same slots.
        __syncthreads();
        if (CONV == 2) stage_pair(sh, sl, Sp, 64, 32, pbase);
        else           stage_pair(sh, sl, RHp, 32, 0, pbase);
        __syncthreads();
#pragma unroll
        for (int s = 9; s < 18; ++s) KSTEP(s, s - 9)
    }

    // ---- epilogue. C layout: col(n)=lane&15, row(pixel)=q*4+reg ----
    const int prow = row0p + wv;   // image row of this wave's pixels
    if (GATES) {
        // h for r*h comes from LDS: conv0 -> h0 (phase A), conv2 -> h1 (phase B)
#pragma unroll
        for (int mg = 0; mg < 2; ++mg)
#pragma unroll
            for (int ng = 0; ng < NG / 2; ++ng)
#pragma unroll
                for (int rg = 0; rg < 4; ++rg) {
                    int lcol = mg * 16 + q * 4 + rg;               // 0..31
                    int psp  = (b * PH + prow + 1) * PH + (col0p + 1 + lcol);
                    int pxp  = (b * HH + prow) * HH + (col0p + lcol);
                    int n    = ng * 16 + m;
                    float rgate = sigmoid_f(acc[mg][ng][rg]);
                    float zgate = sigmoid_f(acc[mg][ng + NG / 2][rg]);
                    int laddr = (((n >> 3) * 6 + (wv + 1)) * 35 + (1 + lcol)) * 8 + (n & 7);
                    float h = b2f(sh[laddr]) + b2f(sl[laddr]);
                    RHp[(long)psp * 32 + n] = packsplit(rgate * h);
                    zbuf[(long)pxp * 32 + n] = zgate;
                }
    } else {
#pragma unroll
        for (int mg = 0; mg < 2; ++mg)
#pragma unroll
            for (int ng = 0; ng < NG; ++ng)
#pragma unroll
                for (int rg = 0; rg < 4; ++rg) {
                    int lcol = mg * 16 + q * 4 + rg;
                    int psp  = (b * PH + prow + 1) * PH + (col0p + 1 + lcol);
                    int pxp  = (b * HH + prow) * HH + (col0p + lcol);
                    int n    = ng * 16 + m;
                    float nv = tanh_f(acc[mg][ng][rg]);
                    float zz = zbuf[(long)pxp * 32 + n];
                    long sidx = (long)psp * 64 + HB + n;
                    float h = unpack2f(Sp[sidx]);
                    Sp[sidx] = packsplit((1.0f - zz) * h + zz * nv);
                }
    }
#undef KSTEP
}

// ---- final: S ch32-63 (h1) -> d_out NCHW fp32 ----
__global__ void final_out(const unsigned int* __restrict__ Sp, float* __restrict__ out)
{
    int i = blockIdx.x * 256 + threadIdx.x;    // B*32*HW = 4194304
    if (i >= BB * 32 * HW) return;
    int pix = i & 16383;
    int t = i >> 14;
    int c = t & 31, b = t >> 5;
    int r = pix >> 7, cc = pix & 127;
    long ps = (long)(b * PH + r + 1) * PH + cc + 1;
    out[i] = unpack2f(Sp[ps * 64 + 32 + c]);
}

extern "C" void kernel_launch(void* const* d_in, const int* in_sizes, int n_in,
                              void* d_out, int out_size, void* d_ws, size_t ws_size,
                              hipStream_t stream)
{
    const float* seq = (const float*)d_in[0];
    const float* gw0 = (const float*)d_in[1];
    const float* gb0 = (const float*)d_in[2];
    const float* cw0 = (const float*)d_in[3];
    const float* cb0 = (const float*)d_in[4];
    const float* gw1 = (const float*)d_in[5];
    const float* gb1 = (const float*)d_in[6];
    const float* cw1 = (const float*)d_in[7];
    const float* cb1 = (const float*)d_in[8];
    float* out = (float*)d_out;

    const size_t NS  = (size_t)BB * PH * PH * 64;    // 8,652,800 u32
    const size_t NRH = (size_t)BB * PH * PH * 32;    // 4,326,400 u32
    const size_t NZ  = (size_t)BB * HH * HH * 32;    // 4,194,304 f32

    char* p = (char*)d_ws;
    unsigned int* Sp  = (unsigned int*)p; p += NS  * 4;
    unsigned int* RHp = (unsigned int*)p; p += NRH * 4;
    float* zbuf       = (float*)p;        p += NZ  * 4;
    unsigned short* WG0h = (unsigned short*)p; p += 20480 * 2;
    unsigned short* WG0l = (unsigned short*)p; p += 20480 * 2;
    unsigned short* WC0h = (unsigned short*)p; p += 10240 * 2;
    unsigned short* WC0l = (unsigned short*)p; p += 10240 * 2;
    unsigned short* WG1h = (unsigned short*)p; p += 36864 * 2;
    unsigned short* WG1l = (unsigned short*)p; p += 36864 * 2;
    unsigned short* WC1h = (unsigned short*)p; p += 18432 * 2;
    unsigned short* WC1l = (unsigned short*)p; p += 18432 * 2;

    // zero S (states + halo) and RH (halo), one contiguous span
    hipMemsetAsync(Sp, 0, (NS + NRH) * 4, stream);

    prep_w<<<(10 * 64 * 32 + 255) / 256, 256, 0, stream>>>(gw0, WG0h, WG0l, 64, 33, 10, 1);
    prep_w<<<(10 * 32 * 32 + 255) / 256, 256, 0, stream>>>(cw0, WC0h, WC0l, 32, 33, 10, 1);
    prep_w<<<(18 * 64 * 32 + 255) / 256, 256, 0, stream>>>(gw1, WG1h, WG1l, 64, 64, 18, 0);
    prep_w<<<(18 * 32 * 32 + 255) / 256, 256, 0, stream>>>(cw1, WC1h, WC1l, 32, 64, 18, 0);

    dim3 grid(128, BB), block(256);
    const long xbs = (long)TT * HW;
    for (int t = 0; t < TT; ++t) {
        const float* xt = seq + (long)t * HW;
        conv_mfma<0><<<grid, block, 0, stream>>>(Sp, RHp, xt, xbs, WG0h, WG0l, gb0, zbuf);
        conv_mfma<1><<<grid, block, 0, stream>>>(Sp, RHp, xt, xbs, WC0h, WC0l, cb0, zbuf);
        conv_mfma<2><<<grid, block, 0, stream>>>(Sp, RHp, xt, xbs, WG1h, WG1l, gb1, zbuf);
        conv_mfma<3><<<grid, block, 0, stream>>>(Sp, RHp, xt, xbs, WC1h, WC1l, cb1, zbuf);
    }
    final_out<<<(BB * 32 * HW + 255) / 256, 256, 0, stream>>>(Sp, out);
}